// Round 4
// baseline (733.803 us; speedup 1.0000x reference)
//
#include <hip/hip_runtime.h>

// BatchedMonomialFactor round 4:
//  - NUMERICS reverted to round-2's proven 6-product bf16x3 split (logit err
//    ~3e-8; round 3's 4-product 2-split at ~1e-5 flipped argmaxes -> 0.875).
//  - STRUCTURE keeps round 3: barrier-free K-loop (no LDS / no syncthreads in
//    GEMM), XCD swizzle (bid&7 -> one Wp slice per XCD L2), base-2 sinkhorn.

#define D_MODEL 1024
#define RDIM 64
#define BDIM 16
#define NBATCH 2048
#define MB 64
#define XS_LD 68

#define XSZ 2097152                    // 2048*1024 elements (per plane)
#define WPSZ 16777216                  // 1024*16384 elements (per plane)
#define WDSZ 1048576                   // 1024*1024 elements (per plane)

// ws byte offsets: 3 planes x, 3 planes Wp, 2 planes Wd, 2 planes Wa
#define OFF_XS   0u
#define OFF_WPS  12582912u             // 3*XSZ*2
#define OFF_WDS  113246208u            // OFF_WPS + 3*WPSZ*2
#define OFF_WAS  117440512u            // OFF_WDS + 2*WDSZ*2
#define WS_NEED  121634816u            // OFF_WAS + 2*WDSZ*2

// logits scale: (1/TAU=2) * log2(e) -> sinkhorn in base-2 log space (exact
// monotone image of the base-e iteration; argmax preserved)
#define LSCALE 2.8853900817779268f

typedef __attribute__((ext_vector_type(8))) short short8;
typedef __attribute__((ext_vector_type(4))) float f32x4;
#define MFMA_BF16 __builtin_amdgcn_mfma_f32_16x16x32_bf16

__device__ __forceinline__ unsigned short f2bf_rne(float f) {
    unsigned u = __float_as_uint(f);
    unsigned r = (u + 0x7fffu + ((u >> 16) & 1u)) >> 16;
    return (unsigned short)r;
}
__device__ __forceinline__ float bf2f(unsigned short s) {
    return __uint_as_float(((unsigned)s) << 16);
}

// ---------------- prep: split x into 3 bf16 planes [s][b][k] ----------------
__global__ void k_split_x(const float* __restrict__ x, unsigned short* __restrict__ XS) {
    const int i = blockIdx.x * 256 + threadIdx.x;
    const float v = x[i];
    const unsigned short s1 = f2bf_rne(v);
    const float r1 = v - bf2f(s1);
    const unsigned short s2 = f2bf_rne(r1);
    const float r2 = r1 - bf2f(s2);
    XS[i] = s1; XS[XSZ + i] = s2; XS[2 * XSZ + i] = f2bf_rne(r2);
}

// ---- prep: split Wp[k][c] -> dst[s][r][ks][n][k], 3 planes -----------------
__global__ void k_split_w(const float* __restrict__ W, unsigned short* __restrict__ dst) {
    __shared__ float tile[32][65];
    const int t = threadIdx.x;
    const int c0 = blockIdx.x * 64;
    const int kt = blockIdx.y;
    #pragma unroll
    for (int i = 0; i < 8; i++) {
        const int k = (t >> 6) * 8 + i;
        tile[k][t & 63] = W[(long)(kt * 32 + k) * 16384 + c0 + (t & 63)];
    }
    __syncthreads();
    #pragma unroll
    for (int i = 0; i < 8; i++) {
        const int cl = (t >> 5) * 8 + i;
        const int c = c0 + cl;
        const int rr = c >> 8, nn = c & 255;
        const int k = t & 31;
        const float v = tile[k][cl];
        const long off = (((long)(rr * 32 + kt) * 256) + nn) * 32 + k;
        const unsigned short s1 = f2bf_rne(v);
        const float r1 = v - bf2f(s1);
        const unsigned short s2 = f2bf_rne(r1);
        const float r2 = r1 - bf2f(s2);
        dst[off] = s1;
        dst[WPSZ + off] = s2;
        dst[2 * (long)WPSZ + off] = f2bf_rne(r2);
    }
}

// fused Wd/Wa split, 2 planes each (blockIdx.z selects source)
__global__ void k_split_w2(const float* __restrict__ Wd, const float* __restrict__ Wa,
                           unsigned short* __restrict__ WDS_, unsigned short* __restrict__ WAS_) {
    __shared__ float tile[32][65];
    const float* W = blockIdx.z ? Wa : Wd;
    unsigned short* dst = blockIdx.z ? WAS_ : WDS_;
    const int t = threadIdx.x;
    const int c0 = blockIdx.x * 64;
    const int kt = blockIdx.y;
    #pragma unroll
    for (int i = 0; i < 8; i++) {
        const int k = (t >> 6) * 8 + i;
        tile[k][t & 63] = W[(long)(kt * 32 + k) * 1024 + c0 + (t & 63)];
    }
    __syncthreads();
    #pragma unroll
    for (int i = 0; i < 8; i++) {
        const int cl = (t >> 5) * 8 + i;
        const int c = c0 + cl;
        const int rr = c >> 4, nn = c & 15;
        const int k = t & 31;
        const float v = tile[k][cl];
        const int off = ((rr * 32 + kt) * 16 + nn) * 32 + k;
        const unsigned short s1 = f2bf_rne(v);
        const float r1 = v - bf2f(s1);
        dst[off] = s1;
        dst[WDSZ + off] = f2bf_rne(r1);
    }
}

// ---------------- main fused MFMA kernel (barrier-free K-loop) --------------
__global__ __launch_bounds__(256, 3)
void bmf_mfma_kernel(const unsigned short* __restrict__ XS,
                     const unsigned short* __restrict__ WPS,
                     const unsigned short* __restrict__ WDS,
                     const unsigned short* __restrict__ WAS,
                     const float* __restrict__ h,
                     float* __restrict__ out)
{
    __shared__ __align__(16) float sm[12800];     // sinkhorn/epilogue only
    float* la   = sm;                             // [32][16][17]
    float* dval = sm + 8704;                      // [1024]
    float* aval = dval + 1024;
    float* hv   = aval + 1024;
    float* hpm  = hv + 1024;

    const int t   = threadIdx.x;
    const int l   = t & 63;
    const int w   = t >> 6;                       // wave 0..3
    const int bid = blockIdx.x;
    // XCD swizzle: xcd = bid&7 processes all 32 bt of one r before moving on
    const int r   = ((bid >> 8) << 3) | (bid & 7);
    const int bt  = (bid >> 3) & 31;
    const int b0  = bt * MB;
    const int quad = l >> 4, l15 = l & 15;

    f32x4 acc[4][4];
    f32x4 acc2[2];
    #pragma unroll
    for (int a = 0; a < 4; a++)
        #pragma unroll
        for (int b = 0; b < 4; b++) acc[a][b] = (f32x4){0.f, 0.f, 0.f, 0.f};
    acc2[0] = (f32x4){0.f, 0.f, 0.f, 0.f};
    acc2[1] = (f32x4){0.f, 0.f, 0.f, 0.f};

    const int isAlpha = w >> 1;
    const int mtPair  = w & 1;
    const unsigned short* WX = isAlpha ? WAS : WDS;

    // A: row b0+mt*16+l15, k = ks*32 + quad*8 (A[m=lane&15][k=quad*8+j])
    const unsigned short* aB0 = XS + (b0 + l15) * 1024 + quad * 8;       // +mt*16384, +ks*32
    const unsigned short* aB1 = aB0 + XSZ;
    const unsigned short* aB2 = aB1 + XSZ;
    // B: slice [n=256][k=32] per (plane, r, ks); lane at n=(w*4+ntl)*16+l15
    const unsigned short* bB0 = WPS + r * 262144 + ((w * 4) * 16 + l15) * 32 + quad * 8; // +ntl*512, +ks*8192, +plane*WPSZ
    const unsigned short* bB1 = bB0 + WPSZ;
    const unsigned short* bB2 = bB1 + WPSZ;
    // w2: slice [n=16][k=32] per (plane, r, ks)
    const unsigned short* wB0 = WX + r * 16384 + l15 * 32 + quad * 8;    // +ks*512
    const unsigned short* wB1 = wB0 + WDSZ;

    for (int ks = 0; ks < 32; ++ks) {
        const int bo = ks * 8192;
        short8 bf0[4], bf1[4], bf2[4];
        #pragma unroll
        for (int ntl = 0; ntl < 4; ntl++) {
            bf0[ntl] = *(const short8*)(bB0 + bo + ntl * 512);
            bf1[ntl] = *(const short8*)(bB1 + bo + ntl * 512);
            bf2[ntl] = *(const short8*)(bB2 + bo + ntl * 512);
        }
        const short8 wf0 = *(const short8*)(wB0 + ks * 512);
        const short8 wf1 = *(const short8*)(wB1 + ks * 512);
        const int ao = ks * 32;
        #pragma unroll
        for (int mt = 0; mt < 4; mt++) {
            const short8 a0 = *(const short8*)(aB0 + mt * 16384 + ao);
            const short8 a1 = *(const short8*)(aB1 + mt * 16384 + ao);
            const short8 a2 = *(const short8*)(aB2 + mt * 16384 + ao);
            #pragma unroll
            for (int ntl = 0; ntl < 4; ntl++) {
                f32x4 c = acc[mt][ntl];
                c = MFMA_BF16(a0, bf0[ntl], c, 0, 0, 0);
                c = MFMA_BF16(a0, bf1[ntl], c, 0, 0, 0);
                c = MFMA_BF16(a1, bf0[ntl], c, 0, 0, 0);
                c = MFMA_BF16(a0, bf2[ntl], c, 0, 0, 0);
                c = MFMA_BF16(a1, bf1[ntl], c, 0, 0, 0);
                c = MFMA_BF16(a2, bf0[ntl], c, 0, 0, 0);
                acc[mt][ntl] = c;
            }
            if ((mt >> 1) == mtPair) {
                const int mi = mt & 1;
                f32x4 c2 = acc2[mi];
                c2 = MFMA_BF16(a0, wf0, c2, 0, 0, 0);
                c2 = MFMA_BF16(a0, wf1, c2, 0, 0, 0);
                c2 = MFMA_BF16(a1, wf0, c2, 0, 0, 0);
                acc2[mi] = c2;
            }
        }
    }

    // ---- persist diag/alpha pre-activations (C/D: row=quad*4+q, col=l15) ----
    {
        float* arr = isAlpha ? aval : dval;
        #pragma unroll
        for (int mi = 0; mi < 2; mi++) {
            #pragma unroll
            for (int q = 0; q < 4; q++) {
                const int row = (mtPair * 2 + mi) * 16 + quad * 4 + q;
                arr[row * 16 + l15] = acc2[mi][q];
            }
        }
    }
    // ---- stage h, zero h_permuted ----
    #pragma unroll
    for (int q = 0; q < 4; q++) {
        const int id  = t + 256 * q;
        const int row = id >> 4, j = id & 15;
        hv[id]  = h[(long)(b0 + row) * D_MODEL + r * BDIM + j];
        hpm[id] = 0.f;
    }
    __syncthreads();

    // ---- sinkhorn (base-2 log space) + argmax + scatter, two halves --------
    for (int half = 0; half < 2; ++half) {
        #pragma unroll
        for (int mi = 0; mi < 2; mi++) {
            const int mt = half * 2 + mi;
            #pragma unroll
            for (int ntl = 0; ntl < 4; ntl++) {
                #pragma unroll
                for (int q = 0; q < 4; q++) {
                    const int ml = mi * 16 + quad * 4 + q;
                    la[ml * 272 + (w * 4 + ntl) * 17 + l15] = acc[mt][ntl][q] * LSCALE;
                }
            }
        }
        __syncthreads();

        for (int it = 0; it < 5; ++it) {
            #pragma unroll
            for (int q = 0; q < 2; q++) {
                const int id = t + 256 * q;
                const int m = id >> 4, i = id & 15;
                float* rowp = la + m * 272 + i * 17;
                float mx = rowp[0];
                #pragma unroll
                for (int j = 1; j < 16; j++) mx = fmaxf(mx, rowp[j]);
                float s = 0.f;
                #pragma unroll
                for (int j = 0; j < 16; j++) s += exp2f(rowp[j] - mx);
                const float lse = mx + log2f(s);
                #pragma unroll
                for (int j = 0; j < 16; j++) rowp[j] -= lse;
            }
            __syncthreads();
            #pragma unroll
            for (int q = 0; q < 2; q++) {
                const int id = t + 256 * q;
                const int m = id >> 4, j = id & 15;
                float* colp = la + m * 272 + j;
                float mx = colp[0];
                #pragma unroll
                for (int i = 1; i < 16; i++) mx = fmaxf(mx, colp[i * 17]);
                float s = 0.f;
                #pragma unroll
                for (int i = 0; i < 16; i++) s += exp2f(colp[i * 17] - mx);
                const float lse = mx + log2f(s);
                #pragma unroll
                for (int i = 0; i < 16; i++) colp[i * 17] -= lse;
            }
            __syncthreads();
        }
        #pragma unroll
        for (int q = 0; q < 2; q++) {
            const int id = t + 256 * q;
            const int m = id >> 4, j = id & 15;
            const float* colp = la + m * 272 + j;
            float best = colp[0]; int bi = 0;
            #pragma unroll
            for (int i = 1; i < 16; i++) {
                const float v = colp[i * 17];
                if (v > best) { best = v; bi = i; }
            }
            const int gm = half * 32 + m;
            atomicAdd(&hpm[gm * 16 + bi], hv[gm * 16 + j]);
        }
        __syncthreads();
    }

    // ---- final: out = sigmoid(A) * tanh(D) * h_permuted ----
    #pragma unroll
    for (int q = 0; q < 4; q++) {
        const int id  = t + 256 * q;
        const int row = id >> 4, i = id & 15;
        const float A  = aval[id];
        const float Dv = dval[id];
        const float sg = 1.0f / (1.0f + expf(-A));
        out[(long)(b0 + row) * D_MODEL + r * BDIM + i] = sg * tanhf(Dv) * hpm[id];
    }
}

// ---------------- fallback: round-1 fp32 kernel (used if ws too small) ------
__global__ __launch_bounds__(256, 2)
void bmf_fused_kernel(const float* __restrict__ x,
                      const float* __restrict__ h,
                      const float* __restrict__ Wp,
                      const float* __restrict__ Wd,
                      const float* __restrict__ Wa,
                      float* __restrict__ out)
{
    __shared__ float sm[15488];
    float* xs   = sm;
    float* wsh  = sm + 32 * XS_LD;
    float* w2s  = wsh + 32 * 256;
    float* la   = sm;
    float* dval = sm + 11392;
    float* aval = dval + 1024;
    float* hv   = aval + 1024;
    float* hpm  = hv + 1024;

    const int t   = threadIdx.x;
    const int bid = blockIdx.x;
    const int r   = bid >> 5;
    const int b0  = (bid & 31) * MB;
    const long rcol0 = (long)r * (BDIM * BDIM);

    const int tr  = t >> 5;
    const int tc  = t & 31;
    const int cAi = tc * 4;
    const int cBi = 128 + tc * 4;
    const int row2 = t >> 2;
    const int c2   = (t & 3) * 8;

    float acc[8][8];
    float acc2[8];
    #pragma unroll
    for (int i = 0; i < 8; i++) {
        acc2[i] = 0.f;
        #pragma unroll
        for (int j = 0; j < 8; j++) acc[i][j] = 0.f;
    }

    for (int ks = 0; ks < D_MODEL / 32; ++ks) {
        const int k0 = ks * 32;
        {
            const int row = t >> 2, kq = t & 3;
            #pragma unroll
            for (int e = 0; e < 2; e++) {
                const int kk = kq * 4 + e * 16;
                const float4 g = *(const float4*)(x + (long)(b0 + row) * D_MODEL + k0 + kk);
                xs[(kk + 0) * XS_LD + row] = g.x;
                xs[(kk + 1) * XS_LD + row] = g.y;
                xs[(kk + 2) * XS_LD + row] = g.z;
                xs[(kk + 3) * XS_LD + row] = g.w;
            }
        }
        {
            const int rbase = t >> 6;
            const int colf  = (t & 63) * 4;
            #pragma unroll
            for (int rep = 0; rep < 8; rep++) {
                const int rowk = rbase + rep * 4;
                const float4 g = *(const float4*)(Wp + (long)(k0 + rowk) * (RDIM * BDIM * BDIM) + rcol0 + colf);
                *(float4*)(wsh + rowk * 256 + colf) = g;
            }
        }
        {
            const int kr = t >> 3;
            const int c  = (t & 7) * 4;
            const float* src = (c < 16)
                ? (Wd + (long)(k0 + kr) * D_MODEL + r * BDIM + c)
                : (Wa + (long)(k0 + kr) * D_MODEL + r * BDIM + (c - 16));
            const float4 g = *(const float4*)src;
            *(float4*)(w2s + kr * 32 + c) = g;
        }
        __syncthreads();
        #pragma unroll
        for (int kk = 0; kk < 32; ++kk) {
            const float4 xlo = *(const float4*)(xs + kk * XS_LD + tr * 8);
            const float4 xhi = *(const float4*)(xs + kk * XS_LD + tr * 8 + 4);
            const float4 wA  = *(const float4*)(wsh + kk * 256 + cAi);
            const float4 wB  = *(const float4*)(wsh + kk * 256 + cBi);
            const float xv[8] = {xlo.x, xlo.y, xlo.z, xlo.w, xhi.x, xhi.y, xhi.z, xhi.w};
            #pragma unroll
            for (int ri = 0; ri < 8; ri++) {
                acc[ri][0] += xv[ri] * wA.x; acc[ri][1] += xv[ri] * wA.y;
                acc[ri][2] += xv[ri] * wA.z; acc[ri][3] += xv[ri] * wA.w;
                acc[ri][4] += xv[ri] * wB.x; acc[ri][5] += xv[ri] * wB.y;
                acc[ri][6] += xv[ri] * wB.z; acc[ri][7] += xv[ri] * wB.w;
            }
            const float xv2 = xs[kk * XS_LD + row2];
            const float4 u0 = *(const float4*)(w2s + kk * 32 + c2);
            const float4 u1 = *(const float4*)(w2s + kk * 32 + c2 + 4);
            acc2[0] += xv2 * u0.x; acc2[1] += xv2 * u0.y;
            acc2[2] += xv2 * u0.z; acc2[3] += xv2 * u0.w;
            acc2[4] += xv2 * u1.x; acc2[5] += xv2 * u1.y;
            acc2[6] += xv2 * u1.z; acc2[7] += xv2 * u1.w;
        }
        __syncthreads();
    }

    #pragma unroll
    for (int e = 0; e < 8; e++) {
        const int c = c2 + e;
        if (c < 16) dval[row2 * 16 + c] = acc2[e];
        else        aval[row2 * 16 + (c - 16)] = acc2[e];
    }
    #pragma unroll
    for (int q = 0; q < 4; q++) {
        const int id  = t + 256 * q;
        const int row = id >> 4, j = id & 15;
        hv[id]  = h[(long)(b0 + row) * D_MODEL + r * BDIM + j];
        hpm[id] = 0.f;
    }
    __syncthreads();

    for (int half = 0; half < 2; ++half) {
        if ((tr >> 2) == half) {
            const int mbase = (tr & 3) * 8;
            #pragma unroll
            for (int ri = 0; ri < 8; ri++) {
                const int m = mbase + ri;
                #pragma unroll
                for (int e = 0; e < 8; e++) {
                    const int col = (e < 4) ? (cAi + e) : (cBi + e - 4);
                    la[m * 272 + (col >> 4) * 17 + (col & 15)] = acc[ri][e] * 2.0f;
                }
            }
        }
        __syncthreads();

        for (int it = 0; it < 5; ++it) {
            #pragma unroll
            for (int q = 0; q < 2; q++) {
                const int id = t + 256 * q;
                const int m = id >> 4, i = id & 15;
                float* rowp = la + m * 272 + i * 17;
                float mx = rowp[0];
                #pragma unroll
                for (int j = 1; j < 16; j++) mx = fmaxf(mx, rowp[j]);
                float s = 0.f;
                #pragma unroll
                for (int j = 0; j < 16; j++) s += expf(rowp[j] - mx);
                const float lse = mx + logf(s);
                #pragma unroll
                for (int j = 0; j < 16; j++) rowp[j] -= lse;
            }
            __syncthreads();
            #pragma unroll
            for (int q = 0; q < 2; q++) {
                const int id = t + 256 * q;
                const int m = id >> 4, j = id & 15;
                float* colp = la + m * 272 + j;
                float mx = colp[0];
                #pragma unroll
                for (int i = 1; i < 16; i++) mx = fmaxf(mx, colp[i * 17]);
                float s = 0.f;
                #pragma unroll
                for (int i = 0; i < 16; i++) s += expf(colp[i * 17] - mx);
                const float lse = mx + logf(s);
                #pragma unroll
                for (int i = 0; i < 16; i++) colp[i * 17] -= lse;
            }
            __syncthreads();
        }
        #pragma unroll
        for (int q = 0; q < 2; q++) {
            const int id = t + 256 * q;
            const int m = id >> 4, j = id & 15;
            const float* colp = la + m * 272 + j;
            float best = colp[0]; int bi = 0;
            #pragma unroll
            for (int i = 1; i < 16; i++) {
                const float v = colp[i * 17];
                if (v > best) { best = v; bi = i; }
            }
            const int gm = half * 32 + m;
            atomicAdd(&hpm[gm * 16 + bi], hv[gm * 16 + j]);
        }
        __syncthreads();
    }

    #pragma unroll
    for (int q = 0; q < 4; q++) {
        const int id  = t + 256 * q;
        const int row = id >> 4, i = id & 15;
        const float A  = aval[id];
        const float Dv = dval[id];
        const float sg = 1.0f / (1.0f + expf(-A));
        out[(long)(b0 + row) * D_MODEL + r * BDIM + i] = sg * tanhf(Dv) * hpm[id];
    }
}

extern "C" void kernel_launch(void* const* d_in, const int* in_sizes, int n_in,
                              void* d_out, int out_size, void* d_ws, size_t ws_size,
                              hipStream_t stream) {
    const float* x  = (const float*)d_in[0];
    const float* h  = (const float*)d_in[1];
    const float* Wp = (const float*)d_in[2];
    const float* Wd = (const float*)d_in[3];
    const float* Wa = (const float*)d_in[4];
    float* out = (float*)d_out;

    if (ws_size >= (size_t)WS_NEED) {
        unsigned short* XS  = (unsigned short*)((char*)d_ws + OFF_XS);
        unsigned short* WPS = (unsigned short*)((char*)d_ws + OFF_WPS);
        unsigned short* WDS = (unsigned short*)((char*)d_ws + OFF_WDS);
        unsigned short* WAS = (unsigned short*)((char*)d_ws + OFF_WAS);
        k_split_x<<<dim3(XSZ / 256), dim3(256), 0, stream>>>(x, XS);
        k_split_w<<<dim3(256, 32), dim3(256), 0, stream>>>(Wp, WPS);
        k_split_w2<<<dim3(16, 32, 2), dim3(256), 0, stream>>>(Wd, Wa, WDS, WAS);
        bmf_mfma_kernel<<<dim3(2048), dim3(256), 0, stream>>>(XS, WPS, WDS, WAS, h, out);
    } else {
        bmf_fused_kernel<<<dim3(2048), dim3(256), 0, stream>>>(x, h, Wp, Wd, Wa, out);
    }
}